// Round 1
// baseline (1463.419 us; speedup 1.0000x reference)
//
#include <hip/hip_runtime.h>
#include <hip/hip_bf16.h>
#include <stdint.h>

#define DM   1024
#define LSEQ 2048
#define NB   4

typedef __attribute__((ext_vector_type(8))) short  short8;
typedef __attribute__((ext_vector_type(4))) float  floatx4;

__device__ __forceinline__ ushort f2b(float x) {
    union { float f; uint32_t u; } v; v.f = x;
    uint32_t b = v.u + 0x7FFF + ((v.u >> 16) & 1);   // RNE
    return (ushort)(b >> 16);
}

// ---------------------------------------------------------------- cvt f32->bf16
__global__ __launch_bounds__(256) void cvt_bf16_kernel(const float* __restrict__ in,
                                                       ushort* __restrict__ out, int n8) {
    int i = blockIdx.x * 256 + threadIdx.x;
    if (i >= n8) return;
    const float4* p = (const float4*)in + (size_t)i * 2;
    float4 a = p[0], b = p[1];
    union { ushort us[8]; uint4 v; } o;
    o.us[0] = f2b(a.x); o.us[1] = f2b(a.y); o.us[2] = f2b(a.z); o.us[3] = f2b(a.w);
    o.us[4] = f2b(b.x); o.us[5] = f2b(b.y); o.us[6] = f2b(b.z); o.us[7] = f2b(b.w);
    ((uint4*)out)[i] = o.v;
}

// ---------------------------------------------------------------- bf16 MFMA GEMM (B^T form)
// C[m][n] = sum_k A[m][k] * B[n][k] + bias
// MODE 0: bias[m], store C -> out[b][m][l] with n = b*LSEQ + l  (QKV projections)
// MODE 1: bias[n], store C row-major (M x N)                    (output projection)
template <int MODE>
__global__ __launch_bounds__(256) void gemm_bt(const ushort* __restrict__ Aw,
                                               const ushort* __restrict__ Bw,
                                               const float* __restrict__ bias,
                                               float* __restrict__ Cout,
                                               int M, int N, int K) {
    constexpr int BM = 128, BN = 128, BK = 32;
    __shared__ ushort As[BM * BK];   // 8 KB
    __shared__ ushort Bs[BN * BK];   // 8 KB

    const int tid   = threadIdx.x;
    const int wave  = tid >> 6;
    const int lane  = tid & 63;
    const int qlane = lane & 15;
    const int qk    = lane >> 4;
    const int tn    = blockIdx.x * BN;
    const int tm    = blockIdx.y * BM;
    const int wm    = (wave >> 1) * 64;
    const int wn    = (wave & 1) * 64;

    floatx4 acc[4][4] = {};

    for (int k0 = 0; k0 < K; k0 += BK) {
        __syncthreads();   // protect LDS from previous iteration's readers
#pragma unroll
        for (int j = 0; j < 2; ++j) {
            int chunk = tid + j * 256;          // 512 x 16B chunks per 8KB tile
            int row   = chunk >> 2;             // 4 chunks (64B = 32 bf16) per row
            int col   = (chunk & 3) * 8;        // bf16 element offset in row
            const ushort* gpA = Aw + (size_t)(tm + row) * K + k0 + col;
            const ushort* gpB = Bw + (size_t)(tn + row) * K + k0 + col;
            int base = (j * 256 + wave * 64) * 16;   // wave-uniform LDS byte base
            __builtin_amdgcn_global_load_lds((const __attribute__((address_space(1))) void*)gpA,
                                             (__attribute__((address_space(3))) void*)((char*)As + base),
                                             16, 0, 0);
            __builtin_amdgcn_global_load_lds((const __attribute__((address_space(1))) void*)gpB,
                                             (__attribute__((address_space(3))) void*)((char*)Bs + base),
                                             16, 0, 0);
        }
        __syncthreads();   // drains vmcnt before barrier -> tiles ready

        short8 af[4], bfv[4];
#pragma unroll
        for (int i = 0; i < 4; ++i)
            af[i] = *(const short8*)(As + (wm + i * 16 + qlane) * BK + qk * 8);
#pragma unroll
        for (int j = 0; j < 4; ++j)
            bfv[j] = *(const short8*)(Bs + (wn + j * 16 + qlane) * BK + qk * 8);
#pragma unroll
        for (int i = 0; i < 4; ++i)
#pragma unroll
            for (int j = 0; j < 4; ++j)
                acc[i][j] = __builtin_amdgcn_mfma_f32_16x16x32_bf16(af[i], bfv[j], acc[i][j], 0, 0, 0);
    }

#pragma unroll
    for (int i = 0; i < 4; ++i) {
#pragma unroll
        for (int j = 0; j < 4; ++j) {
#pragma unroll
            for (int r = 0; r < 4; ++r) {
                int m = tm + wm + i * 16 + qk * 4 + r;   // C/D: row=(lane>>4)*4+reg
                int n = tn + wn + j * 16 + qlane;        //      col=lane&15
                float val = acc[i][j][r];
                if (MODE == 0) {
                    val += bias[m];
                    int bb = n >> 11, l = n & (LSEQ - 1);
                    Cout[((size_t)bb * DM + m) * LSEQ + l] = val;
                } else {
                    val += bias[n];
                    Cout[(size_t)m * N + n] = val;
                }
            }
        }
    }
}

// ---------------------------------------------------------------- causal conv + skip + gate
// out[bd][l] = ( sum_{t<=l} ker[d][l-t]*x[bd][t] + scale[d]*x[bd][l] ) * gate[bd][l]
__global__ __launch_bounds__(256) void conv_gate_kernel(const float* __restrict__ x,
                                                        const float* __restrict__ ker,
                                                        const float* __restrict__ scale,
                                                        const float* __restrict__ gate,
                                                        float* __restrict__ out) {
    __shared__ float xs[LSEQ];
    __shared__ float ks[LSEQ];
    const int bd = blockIdx.x;
    const int d  = bd & (DM - 1);
    const float* xrow = x + (size_t)bd * LSEQ;
    const float* krow = ker + (size_t)d * LSEQ;
    const int tid = threadIdx.x;
#pragma unroll
    for (int j = 0; j < 2; ++j) {
        int idx = (tid + j * 256) * 4;
        *(float4*)(xs + idx) = *(const float4*)(xrow + idx);
        *(float4*)(ks + idx) = *(const float4*)(krow + idx);
    }
    __syncthreads();

    const int l0 = tid * 8;
    float acc[8] = {0.f, 0.f, 0.f, 0.f, 0.f, 0.f, 0.f, 0.f};

    for (int tb = 0; tb < l0; tb += 8) {        // full 8x8 blocks, t in [tb,tb+8) all <= every l
        float4 xa = *(const float4*)(xs + tb);
        float4 xb = *(const float4*)(xs + tb + 4);
        const float* kp = ks + (l0 - tb - 8);
        float4 k0v = *(const float4*)(kp);
        float4 k1v = *(const float4*)(kp + 4);
        float4 k2v = *(const float4*)(kp + 8);
        float4 k3v = *(const float4*)(kp + 12);
        float xv[8] = {xa.x, xa.y, xa.z, xa.w, xb.x, xb.y, xb.z, xb.w};
        float kw[16] = {k0v.x, k0v.y, k0v.z, k0v.w, k1v.x, k1v.y, k1v.z, k1v.w,
                        k2v.x, k2v.y, k2v.z, k2v.w, k3v.x, k3v.y, k3v.z, k3v.w};
#pragma unroll
        for (int tt = 0; tt < 8; ++tt)
#pragma unroll
            for (int r = 0; r < 8; ++r)
                acc[r] += kw[8 + r - tt] * xv[tt];   // ker[l0+r-(tb+tt)]
    }
    // diagonal block: t = l0+tt, only outputs r >= tt
#pragma unroll
    for (int tt = 0; tt < 8; ++tt) {
        float xv = xs[l0 + tt];
#pragma unroll
        for (int r = 0; r < 8; ++r)
            if (r >= tt) acc[r] += ks[r - tt] * xv;
    }

    const float sc = scale[d];
    const float* grow = gate + (size_t)bd * LSEQ;
    float* orow = out + (size_t)bd * LSEQ;
#pragma unroll
    for (int r = 0; r < 8; ++r) {
        int l = l0 + r;
        orow[l] = (acc[r] + sc * xs[l]) * grow[l];
    }
}

// ---------------------------------------------------------------- (B,DM,L) f32 -> (B*L,DM) bf16
__global__ __launch_bounds__(256) void transpose_cvt_kernel(const float* __restrict__ in,
                                                            ushort* __restrict__ out) {
    __shared__ float t[32][33];
    const int l0 = blockIdx.x * 32;
    const int d0 = blockIdx.y * 32;
    const int b  = blockIdx.z;
    const int tx = threadIdx.x & 31;
    const int ty = threadIdx.x >> 5;   // 0..7
#pragma unroll
    for (int k = 0; k < 4; ++k) {
        int dd = d0 + ty + k * 8;
        t[ty + k * 8][tx] = in[((size_t)b * DM + dd) * LSEQ + l0 + tx];
    }
    __syncthreads();
#pragma unroll
    for (int k = 0; k < 4; ++k) {
        int ll = l0 + ty + k * 8;
        out[((size_t)b * LSEQ + ll) * DM + d0 + tx] = f2b(t[tx][ty + k * 8]);
    }
}

// ---------------------------------------------------------------- launch
extern "C" void kernel_launch(void* const* d_in, const int* in_sizes, int n_in,
                              void* d_out, int out_size, void* d_ws, size_t ws_size,
                              hipStream_t stream) {
    const float* u        = (const float*)d_in[0];
    const float* Wq       = (const float*)d_in[1];
    const float* bq       = (const float*)d_in[2];
    const float* Wk       = (const float*)d_in[3];
    const float* bk       = (const float*)d_in[4];
    const float* Wv       = (const float*)d_in[5];
    const float* bv       = (const float*)d_in[6];
    const float* k_kernel = (const float*)d_in[7];
    const float* k_D      = (const float*)d_in[8];
    const float* ssm_ker  = (const float*)d_in[9];
    const float* Dv       = (const float*)d_in[10];
    const float* Wo       = (const float*)d_in[11];
    const float* bo       = (const float*)d_in[12];
    float* outp = (float*)d_out;

    char* ws = (char*)d_ws;
    float*  Q    = (float*)(ws);                    // 32 MB
    float*  KV   = (float*)(ws + (32ull << 20));    // 32 MB  (k -> kv -> y*q, in place)
    float*  V    = (float*)(ws + (64ull << 20));    // 32 MB
    ushort* U16  = (ushort*)(ws + (96ull << 20));   // 16 MB  (u bf16; reused later as YT)
    ushort* YT   = (ushort*)(ws + (96ull << 20));   // 16 MB  (yq transposed, bf16)
    ushort* Wq16 = (ushort*)(ws + (112ull << 20));  // 2 MB
    ushort* Wk16 = (ushort*)(ws + (114ull << 20));
    ushort* Wv16 = (ushort*)(ws + (116ull << 20));
    ushort* Wo16 = (ushort*)(ws + (118ull << 20));

    // f32 -> bf16 conversions
    cvt_bf16_kernel<<<(NB * LSEQ * DM / 8) / 256, 256, 0, stream>>>(u, U16, NB * LSEQ * DM / 8);
    cvt_bf16_kernel<<<(DM * DM / 8) / 256, 256, 0, stream>>>(Wq, Wq16, DM * DM / 8);
    cvt_bf16_kernel<<<(DM * DM / 8) / 256, 256, 0, stream>>>(Wk, Wk16, DM * DM / 8);
    cvt_bf16_kernel<<<(DM * DM / 8) / 256, 256, 0, stream>>>(Wv, Wv16, DM * DM / 8);
    cvt_bf16_kernel<<<(DM * DM / 8) / 256, 256, 0, stream>>>(Wo, Wo16, DM * DM / 8);

    // q/k/v projections: M=d (weights as A), N=(b,l), K=h
    dim3 g1(NB * LSEQ / 128, DM / 128);
    gemm_bt<0><<<g1, 256, 0, stream>>>(Wq16, U16, bq, Q,  DM, NB * LSEQ, DM);
    gemm_bt<0><<<g1, 256, 0, stream>>>(Wk16, U16, bk, KV, DM, NB * LSEQ, DM);
    gemm_bt<0><<<g1, 256, 0, stream>>>(Wv16, U16, bv, V,  DM, NB * LSEQ, DM);

    // kv = (k_kernel (*) k + k_D*k) * v      (in place over k)
    conv_gate_kernel<<<NB * DM, 256, 0, stream>>>(KV, k_kernel, k_D, V, KV);
    // yq = (ssm_kernel (*) kv + D*kv) * q    (in place over kv)
    conv_gate_kernel<<<NB * DM, 256, 0, stream>>>(KV, ssm_ker, Dv, Q, KV);

    // (B,DM,L) f32 -> (B*L,DM) bf16
    dim3 g2(LSEQ / 32, DM / 32, NB);
    transpose_cvt_kernel<<<g2, 256, 0, stream>>>(KV, YT);

    // out = YT @ Wo^T + bo : M=(b,l), N=o, K=h
    dim3 g3(DM / 128, NB * LSEQ / 128);
    gemm_bt<1><<<g3, 256, 0, stream>>>(YT, Wo16, bo, outp, NB * LSEQ, DM, DM);
}

// Round 2
// 269.409 us; speedup vs baseline: 5.4320x; 5.4320x over previous
//
#include <hip/hip_runtime.h>
#include <hip/hip_bf16.h>
#include <stdint.h>

#define DM   1024
#define LSEQ 2048
#define NB   4

typedef __attribute__((ext_vector_type(8))) short  short8;
typedef __attribute__((ext_vector_type(4))) float  floatx4;

__device__ __forceinline__ ushort f2b(float x) {
    union { float f; uint32_t u; } v; v.f = x;
    uint32_t b = v.u + 0x7FFF + ((v.u >> 16) & 1);   // RNE
    return (ushort)(b >> 16);
}

// ---------------------------------------------------------------- cvt f32->bf16
__global__ __launch_bounds__(256) void cvt_bf16_kernel(const float* __restrict__ in,
                                                       ushort* __restrict__ out, int n8) {
    int i = blockIdx.x * 256 + threadIdx.x;
    if (i >= n8) return;
    const float4* p = (const float4*)in + (size_t)i * 2;
    float4 a = p[0], b = p[1];
    union { ushort us[8]; uint4 v; } o;
    o.us[0] = f2b(a.x); o.us[1] = f2b(a.y); o.us[2] = f2b(a.z); o.us[3] = f2b(a.w);
    o.us[4] = f2b(b.x); o.us[5] = f2b(b.y); o.us[6] = f2b(b.z); o.us[7] = f2b(b.w);
    ((uint4*)out)[i] = o.v;
}

// ---------------------------------------------------------------- bf16 MFMA GEMM (B^T form)
// C[m][n] = sum_k A[m][k] * B[n][k] + bias
// MODE 0: bias[m], store C -> out[b][m][l] with n = b*LSEQ + l  (QKV projections)
// MODE 1: bias[n], store C row-major (M x N)                    (output projection)
template <int MODE>
__global__ __launch_bounds__(256) void gemm_bt(const ushort* __restrict__ Aw,
                                               const ushort* __restrict__ Bw,
                                               const float* __restrict__ bias,
                                               float* __restrict__ Cout,
                                               int M, int N, int K) {
    constexpr int BM = 128, BN = 128, BK = 32;
    __shared__ ushort As[BM * BK];   // 8 KB
    __shared__ ushort Bs[BN * BK];   // 8 KB

    const int tid   = threadIdx.x;
    const int wave  = tid >> 6;
    const int lane  = tid & 63;
    const int qlane = lane & 15;
    const int qk    = lane >> 4;
    const int tn    = blockIdx.x * BN;
    const int tm    = blockIdx.y * BM;
    const int wm    = (wave >> 1) * 64;
    const int wn    = (wave & 1) * 64;

    floatx4 acc[4][4] = {};

    for (int k0 = 0; k0 < K; k0 += BK) {
        __syncthreads();   // protect LDS from previous iteration's readers
#pragma unroll
        for (int j = 0; j < 2; ++j) {
            int chunk = tid + j * 256;          // 512 x 16B chunks per 8KB tile
            int row   = chunk >> 2;             // 4 chunks (64B = 32 bf16) per row
            int col   = (chunk & 3) * 8;        // bf16 element offset in row
            const ushort* gpA = Aw + (size_t)(tm + row) * K + k0 + col;
            const ushort* gpB = Bw + (size_t)(tn + row) * K + k0 + col;
            int base = (j * 256 + wave * 64) * 16;   // wave-uniform LDS byte base
            __builtin_amdgcn_global_load_lds((const __attribute__((address_space(1))) void*)gpA,
                                             (__attribute__((address_space(3))) void*)((char*)As + base),
                                             16, 0, 0);
            __builtin_amdgcn_global_load_lds((const __attribute__((address_space(1))) void*)gpB,
                                             (__attribute__((address_space(3))) void*)((char*)Bs + base),
                                             16, 0, 0);
        }
        __syncthreads();   // drains vmcnt before barrier -> tiles ready

        short8 af[4], bfv[4];
#pragma unroll
        for (int i = 0; i < 4; ++i)
            af[i] = *(const short8*)(As + (wm + i * 16 + qlane) * BK + qk * 8);
#pragma unroll
        for (int j = 0; j < 4; ++j)
            bfv[j] = *(const short8*)(Bs + (wn + j * 16 + qlane) * BK + qk * 8);
#pragma unroll
        for (int i = 0; i < 4; ++i)
#pragma unroll
            for (int j = 0; j < 4; ++j)
                acc[i][j] = __builtin_amdgcn_mfma_f32_16x16x32_bf16(af[i], bfv[j], acc[i][j], 0, 0, 0);
    }

#pragma unroll
    for (int i = 0; i < 4; ++i) {
#pragma unroll
        for (int j = 0; j < 4; ++j) {
#pragma unroll
            for (int r = 0; r < 4; ++r) {
                int m = tm + wm + i * 16 + qk * 4 + r;   // C/D: row=(lane>>4)*4+reg
                int n = tn + wn + j * 16 + qlane;        //      col=lane&15
                float val = acc[i][j][r];
                if (MODE == 0) {
                    val += bias[m];
                    int bb = n >> 11, l = n & (LSEQ - 1);
                    Cout[((size_t)bb * DM + m) * LSEQ + l] = val;
                } else {
                    val += bias[n];
                    Cout[(size_t)m * N + n] = val;
                }
            }
        }
    }
}

// ---------------------------------------------------------------- MFMA Toeplitz causal conv
// out[b][d][l] = ( sum_{t<=l} ker[d][l-t]*x[b][d][t] + scale[d]*x[b][d][l] ) * gate[b][d][l]
// One workgroup per d; all 4 batches handled as MFMA columns.
// Decomposition: out[16p+i] += sum_tt Kpad[s+i-tt] * xpad[16p-s+tt], s = 0,32,...
// A (16x32 Toeplitz slice of kernel, shared per s) x B (x windows for 16 (b,p) columns).
#define KSTR 2096            // 32 front zeros + 2048 kernel + 16 tail zeros
#define XSTR 2248            // 128 front zeros + 2048 + 32 tail zeros + pad (stride%64==8 -> bank spread)

__global__ __launch_bounds__(256) void conv_mfma_kernel(const float* __restrict__ x,
                                                        const float* __restrict__ ker,
                                                        const float* __restrict__ scale,
                                                        const float* __restrict__ gate,
                                                        float* __restrict__ out) {
    __shared__ ushort ks[KSTR];
    __shared__ ushort xs[4 * XSTR];
    const int d   = blockIdx.x;
    const int tid = threadIdx.x;

    // ---- stage kernel row as bf16 with zero pads
    {
        const float* krow = ker + (size_t)d * LSEQ;
        int t8 = tid * 8;
        float4 a = *(const float4*)(krow + t8);
        float4 b = *(const float4*)(krow + t8 + 4);
        union { ushort us[8]; uint4 v; } o;
        o.us[0] = f2b(a.x); o.us[1] = f2b(a.y); o.us[2] = f2b(a.z); o.us[3] = f2b(a.w);
        o.us[4] = f2b(b.x); o.us[5] = f2b(b.y); o.us[6] = f2b(b.z); o.us[7] = f2b(b.w);
        *(uint4*)(ks + 32 + t8) = o.v;
        uint4 z = {0, 0, 0, 0};
        if (tid < 4) *(uint4*)(ks + 8 * tid) = z;            // front zeros [0,32)
        if (tid >= 4 && tid < 6) *(uint4*)(ks + 2080 + 8 * (tid - 4)) = z;  // tail [2080,2096)
    }
    // ---- stage x rows (4 batches) as bf16 with zero pads
#pragma unroll
    for (int b = 0; b < NB; ++b) {
        const float* xrow = x + ((size_t)b * DM + d) * LSEQ;
        int t8 = tid * 8;
        float4 a = *(const float4*)(xrow + t8);
        float4 c = *(const float4*)(xrow + t8 + 4);
        union { ushort us[8]; uint4 v; } o;
        o.us[0] = f2b(a.x); o.us[1] = f2b(a.y); o.us[2] = f2b(a.z); o.us[3] = f2b(a.w);
        o.us[4] = f2b(c.x); o.us[5] = f2b(c.y); o.us[6] = f2b(c.z); o.us[7] = f2b(c.w);
        *(uint4*)(xs + b * XSTR + 128 + t8) = o.v;
        uint4 z = {0, 0, 0, 0};
        if (tid < 16) *(uint4*)(xs + b * XSTR + 8 * tid) = z;                 // front [0,128)
        if (tid >= 16 && tid < 20) *(uint4*)(xs + b * XSTR + 2176 + 8 * (tid - 16)) = z; // tail
    }
    __syncthreads();

    const int wave = tid >> 6;
    const int lane = tid & 63;
    const int qn   = lane & 15;      // MFMA M/N lane index
    const int qk   = lane >> 4;      // MFMA K-quarter

    // 16 column-groups of 8 p-blocks each; wave w owns {w, 7-w, 8+w, 15-w} (balanced)
    int g[4] = {wave, 7 - wave, 8 + wave, 15 - wave};
    const int smax_all = 128 * (15 - wave) + 128;

    // per-lane B base (ushort index): column n=(b=qn&3, dp=qn>>2), k-offset 8*qk
    const int lbase = (qn & 3) * XSTR + 128 + 16 * (qn >> 2) + 8 * qk;
    const int abase0 = 32 + qn - 8 * qk;

    floatx4 acc[4][2] = {};

    for (int s = 0; s <= smax_all; s += 32) {
        union { ushort u[8]; short8 v; } A;
        int ab = abase0 + s;
#pragma unroll
        for (int j = 0; j < 8; ++j) A.u[j] = ks[ab - j];     // Kpad[s + i - tt]
#pragma unroll
        for (int gi = 0; gi < 4; ++gi) {
            if (s <= 128 * g[gi] + 128) {                    // wave-uniform branch
                int bidx = lbase + 128 * g[gi] - s;
                short8 B0 = *(const short8*)(xs + bidx);
                short8 B1 = *(const short8*)(xs + bidx + 64);
                acc[gi][0] = __builtin_amdgcn_mfma_f32_16x16x32_bf16(A.v, B0, acc[gi][0], 0, 0, 0);
                acc[gi][1] = __builtin_amdgcn_mfma_f32_16x16x32_bf16(A.v, B1, acc[gi][1], 0, 0, 0);
            }
        }
    }

    // ---- epilogue: skip (f32) + gate (f32), in-place-safe store
    const float sc = scale[d];
#pragma unroll
    for (int gi = 0; gi < 4; ++gi) {
#pragma unroll
        for (int m = 0; m < 2; ++m) {
            int p  = 8 * g[gi] + 4 * m + (qn >> 2);
            int b  = qn & 3;
            int l0 = 16 * p + 4 * qk;                        // C/D row = 4*qk + r
            size_t off = ((size_t)b * DM + d) * LSEQ + l0;
            float4 xv = *(const float4*)(x + off);
            float4 gv = *(const float4*)(gate + off);
            float4 ov;
            ov.x = (acc[gi][m][0] + sc * xv.x) * gv.x;
            ov.y = (acc[gi][m][1] + sc * xv.y) * gv.y;
            ov.z = (acc[gi][m][2] + sc * xv.z) * gv.z;
            ov.w = (acc[gi][m][3] + sc * xv.w) * gv.w;
            *(float4*)(out + off) = ov;
        }
    }
}

// ---------------------------------------------------------------- (B,DM,L) f32 -> (B*L,DM) bf16
__global__ __launch_bounds__(256) void transpose_cvt_kernel(const float* __restrict__ in,
                                                            ushort* __restrict__ out) {
    __shared__ float t[32][33];
    const int l0 = blockIdx.x * 32;
    const int d0 = blockIdx.y * 32;
    const int b  = blockIdx.z;
    const int tx = threadIdx.x & 31;
    const int ty = threadIdx.x >> 5;   // 0..7
#pragma unroll
    for (int k = 0; k < 4; ++k) {
        int dd = d0 + ty + k * 8;
        t[ty + k * 8][tx] = in[((size_t)b * DM + dd) * LSEQ + l0 + tx];
    }
    __syncthreads();
#pragma unroll
    for (int k = 0; k < 4; ++k) {
        int ll = l0 + ty + k * 8;
        out[((size_t)b * LSEQ + ll) * DM + d0 + tx] = f2b(t[tx][ty + k * 8]);
    }
}

// ---------------------------------------------------------------- launch
extern "C" void kernel_launch(void* const* d_in, const int* in_sizes, int n_in,
                              void* d_out, int out_size, void* d_ws, size_t ws_size,
                              hipStream_t stream) {
    const float* u        = (const float*)d_in[0];
    const float* Wq       = (const float*)d_in[1];
    const float* bq       = (const float*)d_in[2];
    const float* Wk       = (const float*)d_in[3];
    const float* bk       = (const float*)d_in[4];
    const float* Wv       = (const float*)d_in[5];
    const float* bv       = (const float*)d_in[6];
    const float* k_kernel = (const float*)d_in[7];
    const float* k_D      = (const float*)d_in[8];
    const float* ssm_ker  = (const float*)d_in[9];
    const float* Dv       = (const float*)d_in[10];
    const float* Wo       = (const float*)d_in[11];
    const float* bo       = (const float*)d_in[12];
    float* outp = (float*)d_out;

    char* ws = (char*)d_ws;
    float*  Q    = (float*)(ws);                    // 32 MB
    float*  KV   = (float*)(ws + (32ull << 20));    // 32 MB  (k -> kv -> y*q, in place)
    float*  V    = (float*)(ws + (64ull << 20));    // 32 MB
    ushort* U16  = (ushort*)(ws + (96ull << 20));   // 16 MB  (u bf16; reused later as YT)
    ushort* YT   = (ushort*)(ws + (96ull << 20));   // 16 MB  (yq transposed, bf16)
    ushort* Wq16 = (ushort*)(ws + (112ull << 20));  // 2 MB
    ushort* Wk16 = (ushort*)(ws + (114ull << 20));
    ushort* Wv16 = (ushort*)(ws + (116ull << 20));
    ushort* Wo16 = (ushort*)(ws + (118ull << 20));

    // f32 -> bf16 conversions
    cvt_bf16_kernel<<<(NB * LSEQ * DM / 8) / 256, 256, 0, stream>>>(u, U16, NB * LSEQ * DM / 8);
    cvt_bf16_kernel<<<(DM * DM / 8) / 256, 256, 0, stream>>>(Wq, Wq16, DM * DM / 8);
    cvt_bf16_kernel<<<(DM * DM / 8) / 256, 256, 0, stream>>>(Wk, Wk16, DM * DM / 8);
    cvt_bf16_kernel<<<(DM * DM / 8) / 256, 256, 0, stream>>>(Wv, Wv16, DM * DM / 8);
    cvt_bf16_kernel<<<(DM * DM / 8) / 256, 256, 0, stream>>>(Wo, Wo16, DM * DM / 8);

    // q/k/v projections: M=d (weights as A), N=(b,l), K=h
    dim3 g1(NB * LSEQ / 128, DM / 128);
    gemm_bt<0><<<g1, 256, 0, stream>>>(Wq16, U16, bq, Q,  DM, NB * LSEQ, DM);
    gemm_bt<0><<<g1, 256, 0, stream>>>(Wk16, U16, bk, KV, DM, NB * LSEQ, DM);
    gemm_bt<0><<<g1, 256, 0, stream>>>(Wv16, U16, bv, V,  DM, NB * LSEQ, DM);

    // kv = (k_kernel (*) k + k_D*k) * v      (MFMA Toeplitz conv, in place over k)
    conv_mfma_kernel<<<DM, 256, 0, stream>>>(KV, k_kernel, k_D, V, KV);
    // yq = (ssm_kernel (*) kv + D*kv) * q    (in place over kv)
    conv_mfma_kernel<<<DM, 256, 0, stream>>>(KV, ssm_ker, Dv, Q, KV);

    // (B,DM,L) f32 -> (B*L,DM) bf16
    dim3 g2(LSEQ / 32, DM / 32, NB);
    transpose_cvt_kernel<<<g2, 256, 0, stream>>>(KV, YT);

    // out = YT @ Wo^T + bo : M=(b,l), N=o, K=h
    dim3 g3(DM / 128, NB * LSEQ / 128);
    gemm_bt<1><<<g3, 256, 0, stream>>>(YT, Wo16, bo, outp, NB * LSEQ, DM, DM);
}

// Round 3
// 203.491 us; speedup vs baseline: 7.1916x; 1.3239x over previous
//
#include <hip/hip_runtime.h>
#include <hip/hip_bf16.h>
#include <stdint.h>

#define DM   1024
#define LSEQ 2048
#define NB   4

typedef __attribute__((ext_vector_type(8))) short  short8;
typedef __attribute__((ext_vector_type(4))) float  floatx4;

__device__ __forceinline__ ushort f2b(float x) {
    union { float f; uint32_t u; } v; v.f = x;
    uint32_t b = v.u + 0x7FFF + ((v.u >> 16) & 1);   // RNE
    return (ushort)(b >> 16);
}

// ---------------------------------------------------------------- cvt f32->bf16 (u)
__global__ __launch_bounds__(256) void cvt_bf16_kernel(const float* __restrict__ in,
                                                       ushort* __restrict__ out, int n8) {
    int i = blockIdx.x * 256 + threadIdx.x;
    if (i >= n8) return;
    const float4* p = (const float4*)in + (size_t)i * 2;
    float4 a = p[0], b = p[1];
    union { ushort us[8]; uint4 v; } o;
    o.us[0] = f2b(a.x); o.us[1] = f2b(a.y); o.us[2] = f2b(a.z); o.us[3] = f2b(a.w);
    o.us[4] = f2b(b.x); o.us[5] = f2b(b.y); o.us[6] = f2b(b.z); o.us[7] = f2b(b.w);
    ((uint4*)out)[i] = o.v;
}

// ---------------------------------------------------------------- fused weight cvt (Wq|Wk|Wv|Wo -> one bf16 buffer)
__global__ __launch_bounds__(256) void cvt_w_kernel(const float* __restrict__ Wq,
                                                    const float* __restrict__ Wk,
                                                    const float* __restrict__ Wv,
                                                    const float* __restrict__ Wo,
                                                    ushort* __restrict__ dst) {
    const int per = DM * DM / 8;                      // 8-element chunks per matrix
    int i = blockIdx.x * 256 + threadIdx.x;           // 0 .. 4*per-1
    int r = i / per;                                  // uniform per block (per%256==0)
    const float* src = (r == 0) ? Wq : (r == 1) ? Wk : (r == 2) ? Wv : Wo;
    int j = i - r * per;
    const float4* p = (const float4*)src + (size_t)j * 2;
    float4 a = p[0], b = p[1];
    union { ushort us[8]; uint4 v; } o;
    o.us[0] = f2b(a.x); o.us[1] = f2b(a.y); o.us[2] = f2b(a.z); o.us[3] = f2b(a.w);
    o.us[4] = f2b(b.x); o.us[5] = f2b(b.y); o.us[6] = f2b(b.z); o.us[7] = f2b(b.w);
    ((uint4*)dst)[i] = o.v;
}

// ---------------------------------------------------------------- bf16 MFMA GEMM (B^T form)
// C[m][n] = sum_k A[m][k] * B[n][k] + bias[n]
// MODE 0 (fused QKV): m=(b,l), n = proj*1024+d ; store f32x4 along l into C0/C1/C2 (b,d,l) layout
// MODE 1 (out-proj): store C row-major (M x N) into C0
template <int MODE>
__global__ __launch_bounds__(256) void gemm_bt(const ushort* __restrict__ Aw,
                                               const ushort* __restrict__ Bw,
                                               const float* __restrict__ b0,
                                               const float* __restrict__ b1,
                                               const float* __restrict__ b2,
                                               float* __restrict__ C0,
                                               float* __restrict__ C1,
                                               float* __restrict__ C2,
                                               int M, int N, int K, int nbx) {
    constexpr int BM = 128, BN = 128, BK = 32;
    __shared__ ushort As[BM * BK];   // 8 KB
    __shared__ ushort Bs[BN * BK];   // 8 KB

    const int tid   = threadIdx.x;
    const int wave  = tid >> 6;
    const int lane  = tid & 63;
    const int qlane = lane & 15;
    const int qk    = lane >> 4;

    // bijective XCD swizzle (nwg % 8 == 0 in all our launches)
    int flat = blockIdx.y * nbx + blockIdx.x;
    int nwg  = nbx * gridDim.y;
    int swz  = (flat & 7) * (nwg >> 3) + (flat >> 3);
    const int tn = (swz % nbx) * BN;
    const int tm = (swz / nbx) * BM;

    const int wm = (wave >> 1) * 64;
    const int wn = (wave & 1) * 64;

    floatx4 acc[4][4] = {};

    for (int k0 = 0; k0 < K; k0 += BK) {
        __syncthreads();   // protect LDS from previous iteration's readers
#pragma unroll
        for (int j = 0; j < 2; ++j) {
            int chunk = tid + j * 256;          // 512 x 16B chunks per 8KB tile
            int row   = chunk >> 2;             // 4 chunks (64B = 32 bf16) per row
            int col   = (chunk & 3) * 8;        // bf16 element offset in row
            const ushort* gpA = Aw + (size_t)(tm + row) * K + k0 + col;
            const ushort* gpB = Bw + (size_t)(tn + row) * K + k0 + col;
            int base = (j * 256 + wave * 64) * 16;   // wave-uniform LDS byte base
            __builtin_amdgcn_global_load_lds((const __attribute__((address_space(1))) void*)gpA,
                                             (__attribute__((address_space(3))) void*)((char*)As + base),
                                             16, 0, 0);
            __builtin_amdgcn_global_load_lds((const __attribute__((address_space(1))) void*)gpB,
                                             (__attribute__((address_space(3))) void*)((char*)Bs + base),
                                             16, 0, 0);
        }
        __syncthreads();   // drains vmcnt before barrier -> tiles ready

        short8 af[4], bfv[4];
#pragma unroll
        for (int i = 0; i < 4; ++i)
            af[i] = *(const short8*)(As + (wm + i * 16 + qlane) * BK + qk * 8);
#pragma unroll
        for (int j = 0; j < 4; ++j)
            bfv[j] = *(const short8*)(Bs + (wn + j * 16 + qlane) * BK + qk * 8);
#pragma unroll
        for (int i = 0; i < 4; ++i)
#pragma unroll
            for (int j = 0; j < 4; ++j)
                acc[i][j] = __builtin_amdgcn_mfma_f32_16x16x32_bf16(af[i], bfv[j], acc[i][j], 0, 0, 0);
    }

#pragma unroll
    for (int i = 0; i < 4; ++i) {
#pragma unroll
        for (int j = 0; j < 4; ++j) {
            int n  = tn + wn + j * 16 + qlane;       // C/D col = lane&15
            int m0 = tm + wm + i * 16 + qk * 4;      // C/D row = (lane>>4)*4 + r
            if (MODE == 0) {
                int proj = n >> 10, dd = n & (DM - 1);
                const float* bb = (proj == 0) ? b0 : (proj == 1) ? b1 : b2;
                float* Cb       = (proj == 0) ? C0 : (proj == 1) ? C1 : C2;
                float bv = bb[dd];
                int b = m0 >> 11, l = m0 & (LSEQ - 1);
                float4 val;
                val.x = acc[i][j][0] + bv;
                val.y = acc[i][j][1] + bv;
                val.z = acc[i][j][2] + bv;
                val.w = acc[i][j][3] + bv;
                *(float4*)(Cb + ((size_t)b * DM + dd) * LSEQ + l) = val;
            } else {
                float bv = b0[n];
#pragma unroll
                for (int r = 0; r < 4; ++r)
                    C0[(size_t)(m0 + r) * N + n] = acc[i][j][r] + bv;
            }
        }
    }
}

// ---------------------------------------------------------------- MFMA Toeplitz causal conv
// out[b][d][l] = ( sum_{t<=l} ker[d][l-t]*x[b][d][t] + scale[d]*x[b][d][l] ) * gate[b][d][l]
// A-fragments built from REVERSED kernel (krev) via aligned b64 reads + alignbit funnel;
// B-fragments use 2-deep rolling register reuse (B1(t) == B0(t-2)).
#define KSTR 2096            // krev: 16 front zeros + 2048 reversed kernel + 32 tail zeros
#define XSTR 2248            // 128 front zeros + 2048 + 32 tail zeros + pad

__global__ __launch_bounds__(256) void conv_mfma_kernel(const float* __restrict__ x,
                                                        const float* __restrict__ ker,
                                                        const float* __restrict__ scale,
                                                        const float* __restrict__ gate,
                                                        float* __restrict__ out) {
    __shared__ ushort krev[KSTR];
    __shared__ ushort xs[4 * XSTR];
    const int d   = blockIdx.x;
    const int tid = threadIdx.x;

    // ---- stage REVERSED kernel row as bf16: krev[i] = Kpad[2095-i], Kpad = {32 zeros, ker, 16 zeros}
    {
        const float* krow = ker + (size_t)d * LSEQ;
        int t8 = tid * 8;
        float4 a = *(const float4*)(krow + t8);
        float4 b = *(const float4*)(krow + t8 + 4);
        union { ushort us[8]; uint4 v; } o;                 // reversed order
        o.us[0] = f2b(b.w); o.us[1] = f2b(b.z); o.us[2] = f2b(b.y); o.us[3] = f2b(b.x);
        o.us[4] = f2b(a.w); o.us[5] = f2b(a.z); o.us[6] = f2b(a.y); o.us[7] = f2b(a.x);
        *(uint4*)(krev + (2056 - t8)) = o.v;
        uint4 z = {0, 0, 0, 0};
        if (tid < 2) *(uint4*)(krev + 8 * tid) = z;                   // [0,16)
        if (tid >= 2 && tid < 6) *(uint4*)(krev + 2064 + 8 * (tid - 2)) = z;  // [2064,2096)
    }
    // ---- stage x rows (4 batches) as bf16 with zero pads
#pragma unroll
    for (int b = 0; b < NB; ++b) {
        const float* xrow = x + ((size_t)b * DM + d) * LSEQ;
        int t8 = tid * 8;
        float4 a = *(const float4*)(xrow + t8);
        float4 c = *(const float4*)(xrow + t8 + 4);
        union { ushort us[8]; uint4 v; } o;
        o.us[0] = f2b(a.x); o.us[1] = f2b(a.y); o.us[2] = f2b(a.z); o.us[3] = f2b(a.w);
        o.us[4] = f2b(c.x); o.us[5] = f2b(c.y); o.us[6] = f2b(c.z); o.us[7] = f2b(c.w);
        *(uint4*)(xs + b * XSTR + 128 + t8) = o.v;
        uint4 z = {0, 0, 0, 0};
        if (tid < 16) *(uint4*)(xs + b * XSTR + 8 * tid) = z;                 // front [0,128)
        if (tid >= 16 && tid < 20) *(uint4*)(xs + b * XSTR + 2176 + 8 * (tid - 16)) = z; // tail
    }
    __syncthreads();

    const int wave = tid >> 6;
    const int lane = tid & 63;
    const int qn   = lane & 15;      // MFMA M/N lane index
    const int qk   = lane >> 4;      // MFMA K-quarter

    // 16 column-groups of 8 p-blocks each; wave w owns {w, 7-w, 8+w, 15-w} (balanced)
    int g[4] = {wave, 7 - wave, 8 + wave, 15 - wave};
    const int smax_all = 128 * (15 - wave) + 128;    // multiple of 128

    // per-lane B base (ushort index): column n=(b=qn&3, dp=qn>>2), k-offset 8*qk
    const int lbase = (qn & 3) * XSTR + 128 + 16 * (qn >> 2) + 8 * qk;

    floatx4 acc[4][2] = {};

    // rolling B prologue: fE[g] = F(128g+64) (used at s=0), fO[g] = F(128g+32) (used at s=32)
    short8 fE[4], fO[4];
#pragma unroll
    for (int gi = 0; gi < 4; ++gi) {
        fE[gi] = *(const short8*)(xs + lbase + 128 * g[gi] + 64);
        fO[gi] = *(const short8*)(xs + lbase + 128 * g[gi] + 32);
    }

    // A(s).u[j] = Kpad[s + qn - 8*qk - j] = krev[b_el + j], b_el = 2063 - qn + 8*qk - s
#define CSTEP(SS, FP)                                                                        \
    {                                                                                        \
        int b_el = 2063 - qn + 8 * qk - (SS);                                                \
        int A0 = b_el & ~3;                                                                  \
        uint2 w0 = *(const uint2*)(krev + A0);                                               \
        uint2 w1 = *(const uint2*)(krev + A0 + 4);                                           \
        uint2 w2 = *(const uint2*)(krev + A0 + 8);                                           \
        int qsel = (b_el >> 1) & 1;                                                          \
        uint sh  = (uint)(b_el & 1) * 16u;                                                   \
        uint e0 = qsel ? w0.y : w0.x;                                                        \
        uint e1 = qsel ? w1.x : w0.y;                                                        \
        uint e2 = qsel ? w1.y : w1.x;                                                        \
        uint e3 = qsel ? w2.x : w1.y;                                                        \
        uint e4 = qsel ? w2.y : w2.x;                                                        \
        union { uint u[4]; short8 v; } Af;                                                   \
        Af.u[0] = __builtin_amdgcn_alignbit(e1, e0, sh);                                     \
        Af.u[1] = __builtin_amdgcn_alignbit(e2, e1, sh);                                     \
        Af.u[2] = __builtin_amdgcn_alignbit(e3, e2, sh);                                     \
        Af.u[3] = __builtin_amdgcn_alignbit(e4, e3, sh);                                     \
        _Pragma("unroll")                                                                    \
        for (int gi = 0; gi < 4; ++gi) {                                                     \
            if ((SS) <= 128 * g[gi] + 128) {                                                 \
                short8 fN = *(const short8*)(xs + lbase + 128 * g[gi] - (SS));               \
                acc[gi][0] = __builtin_amdgcn_mfma_f32_16x16x32_bf16(Af.v, fN, acc[gi][0], 0, 0, 0); \
                acc[gi][1] = __builtin_amdgcn_mfma_f32_16x16x32_bf16(Af.v, FP[gi], acc[gi][1], 0, 0, 0); \
                FP[gi] = fN;                                                                 \
            }                                                                                \
        }                                                                                    \
    }

    for (int s = 0; s <= smax_all; s += 64) {
        CSTEP(s, fE);
        if (s + 32 <= smax_all) CSTEP(s + 32, fO);
    }
#undef CSTEP

    // ---- epilogue: skip (f32) + gate (f32), in-place-safe store
    const float sc = scale[d];
#pragma unroll
    for (int gi = 0; gi < 4; ++gi) {
#pragma unroll
        for (int m = 0; m < 2; ++m) {
            int p  = 8 * g[gi] + 4 * m + (qn >> 2);
            int b  = qn & 3;
            int l0 = 16 * p + 4 * qk;                        // C/D row = 4*qk + r
            size_t off = ((size_t)b * DM + d) * LSEQ + l0;
            float4 xv = *(const float4*)(x + off);
            float4 gv = *(const float4*)(gate + off);
            float4 ov;
            ov.x = (acc[gi][m][0] + sc * xv.x) * gv.x;
            ov.y = (acc[gi][m][1] + sc * xv.y) * gv.y;
            ov.z = (acc[gi][m][2] + sc * xv.z) * gv.z;
            ov.w = (acc[gi][m][3] + sc * xv.w) * gv.w;
            *(float4*)(out + off) = ov;
        }
    }
}

// ---------------------------------------------------------------- (B,DM,L) f32 -> (B*L,DM) bf16
__global__ __launch_bounds__(256) void transpose_cvt_kernel(const float* __restrict__ in,
                                                            ushort* __restrict__ out) {
    __shared__ float t[32][33];
    const int l0 = blockIdx.x * 32;
    const int d0 = blockIdx.y * 32;
    const int b  = blockIdx.z;
    const int tx = threadIdx.x & 31;
    const int ty = threadIdx.x >> 5;   // 0..7
#pragma unroll
    for (int k = 0; k < 4; ++k) {
        int dd = d0 + ty + k * 8;
        t[ty + k * 8][tx] = in[((size_t)b * DM + dd) * LSEQ + l0 + tx];
    }
    __syncthreads();
#pragma unroll
    for (int k = 0; k < 4; ++k) {
        int ll = l0 + ty + k * 8;
        out[((size_t)b * LSEQ + ll) * DM + d0 + tx] = f2b(t[tx][ty + k * 8]);
    }
}

// ---------------------------------------------------------------- launch
extern "C" void kernel_launch(void* const* d_in, const int* in_sizes, int n_in,
                              void* d_out, int out_size, void* d_ws, size_t ws_size,
                              hipStream_t stream) {
    const float* u        = (const float*)d_in[0];
    const float* Wq       = (const float*)d_in[1];
    const float* bq       = (const float*)d_in[2];
    const float* Wk       = (const float*)d_in[3];
    const float* bk       = (const float*)d_in[4];
    const float* Wv       = (const float*)d_in[5];
    const float* bv       = (const float*)d_in[6];
    const float* k_kernel = (const float*)d_in[7];
    const float* k_D      = (const float*)d_in[8];
    const float* ssm_ker  = (const float*)d_in[9];
    const float* Dv       = (const float*)d_in[10];
    const float* Wo       = (const float*)d_in[11];
    const float* bo       = (const float*)d_in[12];
    float* outp = (float*)d_out;

    char* ws = (char*)d_ws;
    float*  Q    = (float*)(ws);                    // 32 MB
    float*  KV   = (float*)(ws + (32ull << 20));    // 32 MB  (k -> kv -> y*q, in place)
    float*  V    = (float*)(ws + (64ull << 20));    // 32 MB
    ushort* U16  = (ushort*)(ws + (96ull << 20));   // 16 MB  (u bf16; reused later as YT)
    ushort* YT   = (ushort*)(ws + (96ull << 20));   // 16 MB  (yq transposed, bf16)
    ushort* Wcat = (ushort*)(ws + (112ull << 20));  // 8 MB   (Wq|Wk|Wv|Wo bf16)

    // f32 -> bf16 conversions
    cvt_bf16_kernel<<<(NB * LSEQ * DM / 8) / 256, 256, 0, stream>>>(u, U16, NB * LSEQ * DM / 8);
    cvt_w_kernel<<<(4 * DM * DM / 8) / 256, 256, 0, stream>>>(Wq, Wk, Wv, Wo, Wcat);

    // fused q/k/v projection: M=(b,l)=8192, N=3*DM, K=DM
    dim3 g1(3 * DM / 128, NB * LSEQ / 128);
    gemm_bt<0><<<g1, 256, 0, stream>>>(U16, Wcat, bq, bk, bv, Q, KV, V,
                                       NB * LSEQ, 3 * DM, DM, 3 * DM / 128);

    // kv = (k_kernel (*) k + k_D*k) * v      (MFMA Toeplitz conv, in place over k)
    conv_mfma_kernel<<<DM, 256, 0, stream>>>(KV, k_kernel, k_D, V, KV);
    // yq = (ssm_kernel (*) kv + D*kv) * q    (in place over kv)
    conv_mfma_kernel<<<DM, 256, 0, stream>>>(KV, ssm_ker, Dv, Q, KV);

    // (B,DM,L) f32 -> (B*L,DM) bf16
    dim3 g2(LSEQ / 32, DM / 32, NB);
    transpose_cvt_kernel<<<g2, 256, 0, stream>>>(KV, YT);

    // out = YT @ Wo^T + bo : M=(b,l), N=o, K=h
    dim3 g3(DM / 128, NB * LSEQ / 128);
    gemm_bt<1><<<g3, 256, 0, stream>>>(YT, Wcat + 3 * DM * DM, bo, bo, bo,
                                       outp, outp, outp, NB * LSEQ, DM, DM, DM / 128);
}

// Round 4
// 185.732 us; speedup vs baseline: 7.8792x; 1.0956x over previous
//
#include <hip/hip_runtime.h>
#include <hip/hip_bf16.h>
#include <stdint.h>

#define DM   1024
#define LSEQ 2048
#define NB   4

typedef __attribute__((ext_vector_type(8))) short  short8;
typedef __attribute__((ext_vector_type(4))) float  floatx4;

__device__ __forceinline__ ushort f2b(float x) {
    union { float f; uint32_t u; } v; v.f = x;
    uint32_t b = v.u + 0x7FFF + ((v.u >> 16) & 1);   // RNE
    return (ushort)(b >> 16);
}
__device__ __forceinline__ float b2f(ushort x) {
    union { uint32_t u; float f; } v; v.u = ((uint32_t)x) << 16;
    return v.f;
}

// ---------------------------------------------------------------- cvt f32->bf16 (u)
__global__ __launch_bounds__(256) void cvt_bf16_kernel(const float* __restrict__ in,
                                                       ushort* __restrict__ out, int n8) {
    int i = blockIdx.x * 256 + threadIdx.x;
    if (i >= n8) return;
    const float4* p = (const float4*)in + (size_t)i * 2;
    float4 a = p[0], b = p[1];
    union { ushort us[8]; uint4 v; } o;
    o.us[0] = f2b(a.x); o.us[1] = f2b(a.y); o.us[2] = f2b(a.z); o.us[3] = f2b(a.w);
    o.us[4] = f2b(b.x); o.us[5] = f2b(b.y); o.us[6] = f2b(b.z); o.us[7] = f2b(b.w);
    ((uint4*)out)[i] = o.v;
}

// ---------------------------------------------------------------- fused weight cvt
__global__ __launch_bounds__(256) void cvt_w_kernel(const float* __restrict__ Wq,
                                                    const float* __restrict__ Wk,
                                                    const float* __restrict__ Wv,
                                                    const float* __restrict__ Wo,
                                                    ushort* __restrict__ dst) {
    const int per = DM * DM / 8;
    int i = blockIdx.x * 256 + threadIdx.x;
    int r = i / per;                                  // uniform per block
    const float* src = (r == 0) ? Wq : (r == 1) ? Wk : (r == 2) ? Wv : Wo;
    int j = i - r * per;
    const float4* p = (const float4*)src + (size_t)j * 2;
    float4 a = p[0], b = p[1];
    union { ushort us[8]; uint4 v; } o;
    o.us[0] = f2b(a.x); o.us[1] = f2b(a.y); o.us[2] = f2b(a.z); o.us[3] = f2b(a.w);
    o.us[4] = f2b(b.x); o.us[5] = f2b(b.y); o.us[6] = f2b(b.z); o.us[7] = f2b(b.w);
    ((uint4*)dst)[i] = o.v;
}

// ---------------------------------------------------------------- bf16 MFMA GEMM (B^T form)
// C[m][n] = sum_k A[m][k] * B[n][k] + bias
// MODE 0 (fused QKV): m=(b,l), n=proj*1024+d ; store BF16 x4 along l into C0/C1/C2 (b,d,l)
// MODE 1 (out-proj): bias[n]; store f32 row-major (M x N) into C0
template <int MODE>
__global__ __launch_bounds__(256) void gemm_bt(const ushort* __restrict__ Aw,
                                               const ushort* __restrict__ Bw,
                                               const float* __restrict__ b0,
                                               const float* __restrict__ b1,
                                               const float* __restrict__ b2,
                                               void* __restrict__ C0v,
                                               void* __restrict__ C1v,
                                               void* __restrict__ C2v,
                                               int M, int N, int K, int nbx) {
    constexpr int BM = 128, BN = 128, BK = 32;
    __shared__ ushort As[BM * BK];
    __shared__ ushort Bs[BN * BK];

    const int tid   = threadIdx.x;
    const int wave  = tid >> 6;
    const int lane  = tid & 63;
    const int qlane = lane & 15;
    const int qk    = lane >> 4;

    int flat = blockIdx.y * nbx + blockIdx.x;
    int nwg  = nbx * gridDim.y;
    int swz  = (flat & 7) * (nwg >> 3) + (flat >> 3);
    const int tn = (swz % nbx) * BN;
    const int tm = (swz / nbx) * BM;

    const int wm = (wave >> 1) * 64;
    const int wn = (wave & 1) * 64;

    floatx4 acc[4][4] = {};

    for (int k0 = 0; k0 < K; k0 += BK) {
        __syncthreads();
#pragma unroll
        for (int j = 0; j < 2; ++j) {
            int chunk = tid + j * 256;
            int row   = chunk >> 2;
            int col   = (chunk & 3) * 8;
            const ushort* gpA = Aw + (size_t)(tm + row) * K + k0 + col;
            const ushort* gpB = Bw + (size_t)(tn + row) * K + k0 + col;
            int base = (j * 256 + wave * 64) * 16;
            __builtin_amdgcn_global_load_lds((const __attribute__((address_space(1))) void*)gpA,
                                             (__attribute__((address_space(3))) void*)((char*)As + base),
                                             16, 0, 0);
            __builtin_amdgcn_global_load_lds((const __attribute__((address_space(1))) void*)gpB,
                                             (__attribute__((address_space(3))) void*)((char*)Bs + base),
                                             16, 0, 0);
        }
        __syncthreads();

        short8 af[4], bfv[4];
#pragma unroll
        for (int i = 0; i < 4; ++i)
            af[i] = *(const short8*)(As + (wm + i * 16 + qlane) * BK + qk * 8);
#pragma unroll
        for (int j = 0; j < 4; ++j)
            bfv[j] = *(const short8*)(Bs + (wn + j * 16 + qlane) * BK + qk * 8);
#pragma unroll
        for (int i = 0; i < 4; ++i)
#pragma unroll
            for (int j = 0; j < 4; ++j)
                acc[i][j] = __builtin_amdgcn_mfma_f32_16x16x32_bf16(af[i], bfv[j], acc[i][j], 0, 0, 0);
    }

#pragma unroll
    for (int i = 0; i < 4; ++i) {
#pragma unroll
        for (int j = 0; j < 4; ++j) {
            int n  = tn + wn + j * 16 + qlane;       // C/D col = lane&15
            int m0 = tm + wm + i * 16 + qk * 4;      // C/D row = (lane>>4)*4 + r
            if (MODE == 0) {
                int proj = n >> 10, dd = n & (DM - 1);
                const float* bb = (proj == 0) ? b0 : (proj == 1) ? b1 : b2;
                ushort* Cb      = (ushort*)((proj == 0) ? C0v : (proj == 1) ? C1v : C2v);
                float bv = bb[dd];
                int b = m0 >> 11, l = m0 & (LSEQ - 1);
                ushort4 val;
                val.x = f2b(acc[i][j][0] + bv);
                val.y = f2b(acc[i][j][1] + bv);
                val.z = f2b(acc[i][j][2] + bv);
                val.w = f2b(acc[i][j][3] + bv);
                *(ushort4*)(Cb + ((size_t)b * DM + dd) * LSEQ + l) = val;
            } else {
                float* C0 = (float*)C0v;
                float bv = b0[n];
#pragma unroll
                for (int r = 0; r < 4; ++r)
                    C0[(size_t)(m0 + r) * N + n] = acc[i][j][r] + bv;
            }
        }
    }
}

// ---------------------------------------------------------------- MFMA Toeplitz causal conv (bf16 in/out)
// out[b][d][l] = ( sum_{t<=l} ker[d][l-t]*x[b][d][t] + scale[d]*x[b][d][l] ) * gate[b][d][l]
// 512 threads = 8 waves; wave w owns column-groups {w, 15-w} (balanced: 140 MFMA/wave).
// x rows staged via global_load_lds (bf16, linear); kernel staged REVERSED (krev) for
// aligned-b64 + alignbit A-fragment builds; B-fragments 2-deep rolling register reuse.
#define KSTR 2096            // krev: krev[i] = Kpad[2095-i]; Kpad = 32 zeros | ker | 16 zeros
#define XSTR 2248            // elems: 128 front zeros + 2048 + 32 tail zeros + pad

__global__ __launch_bounds__(512) void conv_mfma_kernel(const ushort* __restrict__ x,
                                                        const float* __restrict__ ker,
                                                        const float* __restrict__ scale,
                                                        const ushort* __restrict__ gate,
                                                        ushort* __restrict__ out) {
    __shared__ ushort krev[KSTR];
    __shared__ ushort xs[4 * XSTR];
    const int d    = blockIdx.x;
    const int tid  = threadIdx.x;
    const int wave = tid >> 6;
    const int lane = tid & 63;

    // ---- stage x rows (4 batches) via global_load_lds: wave w -> batch w>>1, half w&1
    {
        int b = wave >> 1, half = wave & 1;
        const ushort* src = x + ((size_t)b * DM + d) * LSEQ + half * 1024 + lane * 8;
        char* dst = (char*)xs + b * (XSTR * 2) + 256 + half * 2048;
#pragma unroll
        for (int c = 0; c < 2; ++c)
            __builtin_amdgcn_global_load_lds((const __attribute__((address_space(1))) void*)(src + c * 512),
                                             (__attribute__((address_space(3))) void*)(dst + c * 1024),
                                             16, 0, 0);
    }
    // ---- stage reversed kernel as bf16: thread t covers ker[4t..4t+3]
    {
        const float* krow = ker + (size_t)d * LSEQ;
        int e0 = tid * 4;
        float4 kv = *(const float4*)(krow + e0);
        ushort4 o;                                    // krev[2060-e0 + j] = ker[e0+3-j]
        o.x = f2b(kv.w); o.y = f2b(kv.z); o.z = f2b(kv.y); o.w = f2b(kv.x);
        *(ushort4*)(krev + (2060 - e0)) = o;
        uint4 z = {0, 0, 0, 0};
        if (tid < 2)  *(uint4*)((char*)krev + tid * 16) = z;                  // [0,16) shorts
        if (tid >= 2 && tid < 6) *(uint4*)((char*)krev + 4128 + (tid - 2) * 16) = z;  // [2064,2096)
        if (tid >= 64 && tid < 128) {                                         // xs front zeros
            int b = (tid - 64) >> 4, c = (tid - 64) & 15;
            *(uint4*)((char*)xs + b * (XSTR * 2) + c * 16) = z;               // bytes [0,256)
        }
        if (tid >= 128 && tid < 144) {                                        // xs tail zeros
            int b = (tid - 128) >> 2, c = (tid - 128) & 3;
            *(uint4*)((char*)xs + b * (XSTR * 2) + 4352 + c * 16) = z;        // bytes [4352,4416)
        }
    }
    __syncthreads();

    const int qn = lane & 15;
    const int qk = lane >> 4;

    int g[2] = {wave, 15 - wave};
    const int smax_all = 128 * (15 - wave) + 128;    // multiple of 64

    const int lbase = (qn & 3) * XSTR + 128 + 16 * (qn >> 2) + 8 * qk;

    floatx4 acc[2][2] = {};

    short8 fE[2], fO[2];
#pragma unroll
    for (int gi = 0; gi < 2; ++gi) {
        fE[gi] = *(const short8*)(xs + lbase + 128 * g[gi] + 64);
        fO[gi] = *(const short8*)(xs + lbase + 128 * g[gi] + 32);
    }

    // A(s).u[j] = Kpad[s + qn - 8*qk - j] = krev[b_el + j], b_el = 2063 - qn + 8*qk - s
#define CSTEP(SS, FP)                                                                        \
    {                                                                                        \
        int b_el = 2063 - qn + 8 * qk - (SS);                                                \
        int A0 = b_el & ~3;                                                                  \
        uint2 w0 = *(const uint2*)(krev + A0);                                               \
        uint2 w1 = *(const uint2*)(krev + A0 + 4);                                           \
        uint2 w2 = *(const uint2*)(krev + A0 + 8);                                           \
        int qsel = (b_el >> 1) & 1;                                                          \
        uint sh  = (uint)(b_el & 1) * 16u;                                                   \
        uint e0 = qsel ? w0.y : w0.x;                                                        \
        uint e1 = qsel ? w1.x : w0.y;                                                        \
        uint e2 = qsel ? w1.y : w1.x;                                                        \
        uint e3 = qsel ? w2.x : w1.y;                                                        \
        uint e4 = qsel ? w2.y : w2.x;                                                        \
        union { uint u[4]; short8 v; } Af;                                                   \
        Af.u[0] = __builtin_amdgcn_alignbit(e1, e0, sh);                                     \
        Af.u[1] = __builtin_amdgcn_alignbit(e2, e1, sh);                                     \
        Af.u[2] = __builtin_amdgcn_alignbit(e3, e2, sh);                                     \
        Af.u[3] = __builtin_amdgcn_alignbit(e4, e3, sh);                                     \
        _Pragma("unroll")                                                                    \
        for (int gi = 0; gi < 2; ++gi) {                                                     \
            if ((SS) <= 128 * g[gi] + 128) {                                                 \
                short8 fN = *(const short8*)(xs + lbase + 128 * g[gi] - (SS));               \
                acc[gi][0] = __builtin_amdgcn_mfma_f32_16x16x32_bf16(Af.v, fN, acc[gi][0], 0, 0, 0); \
                acc[gi][1] = __builtin_amdgcn_mfma_f32_16x16x32_bf16(Af.v, FP[gi], acc[gi][1], 0, 0, 0); \
                FP[gi] = fN;                                                                 \
            }                                                                                \
        }                                                                                    \
    }

    for (int s = 0; s <= smax_all; s += 64) {
        CSTEP(s, fE);
        if (s + 32 <= smax_all) CSTEP(s + 32, fO);
    }
#undef CSTEP

    // ---- epilogue: skip (bf16 x from LDS) + gate (bf16 global), bf16 store
    const float sc = scale[d];
#pragma unroll
    for (int gi = 0; gi < 2; ++gi) {
#pragma unroll
        for (int m = 0; m < 2; ++m) {
            int p  = 8 * g[gi] + 4 * m + (qn >> 2);
            int b  = qn & 3;
            int l0 = 16 * p + 4 * qk;
            size_t off = ((size_t)b * DM + d) * LSEQ + l0;
            ushort4 xv = *(const ushort4*)(xs + b * XSTR + 128 + l0);
            ushort4 gv = *(const ushort4*)(gate + off);
            ushort4 ov;
            ov.x = f2b((acc[gi][m][0] + sc * b2f(xv.x)) * b2f(gv.x));
            ov.y = f2b((acc[gi][m][1] + sc * b2f(xv.y)) * b2f(gv.y));
            ov.z = f2b((acc[gi][m][2] + sc * b2f(xv.z)) * b2f(gv.z));
            ov.w = f2b((acc[gi][m][3] + sc * b2f(xv.w)) * b2f(gv.w));
            *(ushort4*)(out + off) = ov;
        }
    }
}

// ---------------------------------------------------------------- (B,DM,L) bf16 -> (B*L,DM) bf16
__global__ __launch_bounds__(256) void transpose_bf16(const ushort* __restrict__ in,
                                                      ushort* __restrict__ out) {
    __shared__ ushort t[32][36];
    const int l0 = blockIdx.x * 32;
    const int d0 = blockIdx.y * 32;
    const int b  = blockIdx.z;
    const int q  = threadIdx.x & 7;      // 4-elem chunk
    const int r  = threadIdx.x >> 3;     // 0..31
    *(ushort4*)(&t[r][q * 4]) = *(const ushort4*)(in + ((size_t)b * DM + d0 + r) * LSEQ + l0 + q * 4);
    __syncthreads();
    ushort4 o;
    o.x = t[q * 4 + 0][r]; o.y = t[q * 4 + 1][r]; o.z = t[q * 4 + 2][r]; o.w = t[q * 4 + 3][r];
    *(ushort4*)(out + ((size_t)b * LSEQ + l0 + r) * DM + d0 + q * 4) = o;
}

// ---------------------------------------------------------------- launch
extern "C" void kernel_launch(void* const* d_in, const int* in_sizes, int n_in,
                              void* d_out, int out_size, void* d_ws, size_t ws_size,
                              hipStream_t stream) {
    const float* u        = (const float*)d_in[0];
    const float* Wq       = (const float*)d_in[1];
    const float* bq       = (const float*)d_in[2];
    const float* Wk       = (const float*)d_in[3];
    const float* bk       = (const float*)d_in[4];
    const float* Wv       = (const float*)d_in[5];
    const float* bv       = (const float*)d_in[6];
    const float* k_kernel = (const float*)d_in[7];
    const float* k_D      = (const float*)d_in[8];
    const float* ssm_ker  = (const float*)d_in[9];
    const float* Dv       = (const float*)d_in[10];
    const float* Wo       = (const float*)d_in[11];
    const float* bo       = (const float*)d_in[12];
    float* outp = (float*)d_out;

    char* ws = (char*)d_ws;
    ushort* Q    = (ushort*)(ws);                    // 16 MB (bf16 b,d,l)
    ushort* KV   = (ushort*)(ws + (16ull << 20));    // 16 MB (k -> kv -> yq, in place)
    ushort* V    = (ushort*)(ws + (32ull << 20));    // 16 MB
    ushort* U16  = (ushort*)(ws + (48ull << 20));    // 16 MB (u bf16)
    ushort* YT   = (ushort*)(ws + (64ull << 20));    // 16 MB (yq transposed)
    ushort* Wcat = (ushort*)(ws + (80ull << 20));    // 8 MB  (Wq|Wk|Wv|Wo bf16)

    cvt_bf16_kernel<<<(NB * LSEQ * DM / 8) / 256, 256, 0, stream>>>(u, U16, NB * LSEQ * DM / 8);
    cvt_w_kernel<<<(4 * DM * DM / 8) / 256, 256, 0, stream>>>(Wq, Wk, Wv, Wo, Wcat);

    // fused q/k/v projection: M=(b,l)=8192, N=3*DM, K=DM; bf16 outputs
    dim3 g1(3 * DM / 128, NB * LSEQ / 128);
    gemm_bt<0><<<g1, 256, 0, stream>>>(U16, Wcat, bq, bk, bv, Q, KV, V,
                                       NB * LSEQ, 3 * DM, DM, 3 * DM / 128);

    // kv = (k_kernel (*) k + k_D*k) * v
    conv_mfma_kernel<<<DM, 512, 0, stream>>>(KV, k_kernel, k_D, V, KV);
    // yq = (ssm_kernel (*) kv + D*kv) * q
    conv_mfma_kernel<<<DM, 512, 0, stream>>>(KV, ssm_ker, Dv, Q, KV);

    // (B,DM,L) bf16 -> (B*L,DM) bf16
    dim3 g2(LSEQ / 32, DM / 32, NB);
    transpose_bf16<<<g2, 256, 0, stream>>>(KV, YT);

    // out = YT @ Wo^T + bo : M=(b,l), N=o, K=h ; f32 output
    dim3 g3(DM / 128, NB * LSEQ / 128);
    gemm_bt<1><<<g3, 256, 0, stream>>>(YT, Wcat + 3 * DM * DM, bo, bo, bo,
                                       outp, outp, outp, NB * LSEQ, DM, DM, DM / 128);
}

// Round 5
// 172.196 us; speedup vs baseline: 8.4986x; 1.0786x over previous
//
#include <hip/hip_runtime.h>
#include <hip/hip_bf16.h>
#include <stdint.h>

#define DM   1024
#define LSEQ 2048
#define NB   4

typedef __attribute__((ext_vector_type(8))) short  short8;
typedef __attribute__((ext_vector_type(4))) float  floatx4;

__device__ __forceinline__ ushort f2b(float x) {
    union { float f; uint32_t u; } v; v.f = x;
    uint32_t b = v.u + 0x7FFF + ((v.u >> 16) & 1);   // RNE
    return (ushort)(b >> 16);
}
__device__ __forceinline__ float b2f(ushort x) {
    union { uint32_t u; float f; } v; v.u = ((uint32_t)x) << 16;
    return v.f;
}

// ---------------------------------------------------------------- cvt f32->bf16 (u)
__global__ __launch_bounds__(256) void cvt_bf16_kernel(const float* __restrict__ in,
                                                       ushort* __restrict__ out, int n8) {
    int i = blockIdx.x * 256 + threadIdx.x;
    if (i >= n8) return;
    const float4* p = (const float4*)in + (size_t)i * 2;
    float4 a = p[0], b = p[1];
    union { ushort us[8]; uint4 v; } o;
    o.us[0] = f2b(a.x); o.us[1] = f2b(a.y); o.us[2] = f2b(a.z); o.us[3] = f2b(a.w);
    o.us[4] = f2b(b.x); o.us[5] = f2b(b.y); o.us[6] = f2b(b.z); o.us[7] = f2b(b.w);
    ((uint4*)out)[i] = o.v;
}

// ---------------------------------------------------------------- fused weight cvt
__global__ __launch_bounds__(256) void cvt_w_kernel(const float* __restrict__ Wq,
                                                    const float* __restrict__ Wk,
                                                    const float* __restrict__ Wv,
                                                    const float* __restrict__ Wo,
                                                    ushort* __restrict__ dst) {
    const int per = DM * DM / 8;
    int i = blockIdx.x * 256 + threadIdx.x;
    int r = i / per;                                  // uniform per block
    const float* src = (r == 0) ? Wq : (r == 1) ? Wk : (r == 2) ? Wv : Wo;
    int j = i - r * per;
    const float4* p = (const float4*)src + (size_t)j * 2;
    float4 a = p[0], b = p[1];
    union { ushort us[8]; uint4 v; } o;
    o.us[0] = f2b(a.x); o.us[1] = f2b(a.y); o.us[2] = f2b(a.z); o.us[3] = f2b(a.w);
    o.us[4] = f2b(b.x); o.us[5] = f2b(b.y); o.us[6] = f2b(b.z); o.us[7] = f2b(b.w);
    ((uint4*)dst)[i] = o.v;
}

// ---------------------------------------------------------------- pipelined bf16 MFMA GEMM (B^T form)
// C[m][n] = sum_k A[m][k] * B[n][k] + bias
// Tile 128(M) x 256(N), BK=64, 8 waves (2M x 4N, 64x64 per wave), triple-buffered LDS,
// counted vmcnt (stages stay 2 K-tiles in flight), XOR-swizzled LDS chunks (T2) via
// pre-swizzled global source, setprio around MFMA clusters (T5).
// MODE 0 (fused QKV): m=(b,l), n=proj*1024+d ; store BF16 x4 along l into C0/C1/C2 (b,d,l)
// MODE 1 (out-proj): bias[n]; store f32 row-major (M x N) into C0
template <int MODE>
__global__ __launch_bounds__(512, 2) void gemm_bt2(const ushort* __restrict__ Aw,
                                                   const ushort* __restrict__ Bw,
                                                   const float* __restrict__ b0,
                                                   const float* __restrict__ b1,
                                                   const float* __restrict__ b2,
                                                   void* __restrict__ C0v,
                                                   void* __restrict__ C1v,
                                                   void* __restrict__ C2v,
                                                   int M, int N, int K, int nbx) {
    constexpr int BM = 128, BN = 256, BK = 64;
    constexpr int BUFB = 49152;                 // per-buffer bytes: A 16K + B 32K
    __shared__ char lds[3 * BUFB];              // 144 KB

    const int tid   = threadIdx.x;
    const int wave  = tid >> 6;
    const int lane  = tid & 63;
    const int qlane = lane & 15;
    const int qk    = lane >> 4;

    int flat = blockIdx.y * nbx + blockIdx.x;
    int nwg  = nbx * gridDim.y;
    int swz  = (flat & 7) * (nwg >> 3) + (flat >> 3);
    const int tn = (swz % nbx) * BN;
    const int tm = (swz / nbx) * BM;

    const int wmo = (wave >> 2) * 64;           // wave M offset (0/64)
    const int wno = (wave & 3) * 64;            // wave N offset (0..192)
    const int NT  = K / BK;

    // stage K-tile kt into buffer p. 6 global_load_lds per wave (A:2, B:4).
    // LDS dest linear (wave-uniform base + lane*16); global source column pre-swizzled
    // so that logical chunk c of row r lands at physical slot c^(r&7).
#define STAGE(kt, p)                                                                          \
    {                                                                                         \
        const int k0_ = (kt) * BK;                                                            \
        char* Ab_ = lds + (p) * BUFB;                                                         \
        char* Bb_ = Ab_ + 16384;                                                              \
        _Pragma("unroll")                                                                     \
        for (int j = 0; j < 2; ++j) {                                                         \
            int id = wave * 64 + lane + j * 512;                                              \
            int row = id >> 3, s = id & 7;                                                    \
            const ushort* src = Aw + (size_t)(tm + row) * K + k0_ + ((s ^ (row & 7)) * 8);    \
            __builtin_amdgcn_global_load_lds((const __attribute__((address_space(1))) void*)src, \
                (__attribute__((address_space(3))) void*)(Ab_ + wave * 1024 + j * 8192), 16, 0, 0); \
        }                                                                                     \
        _Pragma("unroll")                                                                     \
        for (int j = 0; j < 4; ++j) {                                                         \
            int id = wave * 64 + lane + j * 512;                                              \
            int row = id >> 3, s = id & 7;                                                    \
            const ushort* src = Bw + (size_t)(tn + row) * K + k0_ + ((s ^ (row & 7)) * 8);    \
            __builtin_amdgcn_global_load_lds((const __attribute__((address_space(1))) void*)src, \
                (__attribute__((address_space(3))) void*)(Bb_ + wave * 1024 + j * 8192), 16, 0, 0); \
        }                                                                                     \
    }

    floatx4 acc[4][4] = {};

    STAGE(0, 0);
    STAGE(1, 1);

    const int z7 = qlane & 7;

    for (int t = 0; t < NT; ++t) {
        const int cur = t % 3;
        if (t < NT - 1) asm volatile("s_waitcnt vmcnt(6)" ::: "memory");
        else            asm volatile("s_waitcnt vmcnt(0)" ::: "memory");
        __builtin_amdgcn_s_barrier();
        __builtin_amdgcn_sched_barrier(0);

        if (t + 2 < NT) STAGE(t + 2, (t + 2) % 3);

        const char* Ab = lds + cur * BUFB;
        const char* Bb = Ab + 16384;
#pragma unroll
        for (int kk = 0; kk < 2; ++kk) {
            const int slot = ((kk * 4 + qk) ^ z7) << 4;
            short8 af[4], bfv[4];
#pragma unroll
            for (int i = 0; i < 4; ++i) {
                int r = wmo + i * 16 + qlane;
                af[i] = *(const short8*)(Ab + r * 128 + slot);
            }
#pragma unroll
            for (int j = 0; j < 4; ++j) {
                int r = wno + j * 16 + qlane;
                bfv[j] = *(const short8*)(Bb + r * 128 + slot);
            }
            __builtin_amdgcn_s_setprio(1);
#pragma unroll
            for (int i = 0; i < 4; ++i)
#pragma unroll
                for (int j = 0; j < 4; ++j)
                    acc[i][j] = __builtin_amdgcn_mfma_f32_16x16x32_bf16(af[i], bfv[j], acc[i][j], 0, 0, 0);
            __builtin_amdgcn_s_setprio(0);
        }
    }
#undef STAGE

#pragma unroll
    for (int i = 0; i < 4; ++i) {
#pragma unroll
        for (int j = 0; j < 4; ++j) {
            int n  = tn + wno + j * 16 + qlane;      // C/D col = lane&15
            int m0 = tm + wmo + i * 16 + qk * 4;     // C/D row = (lane>>4)*4 + r
            if (MODE == 0) {
                int proj = n >> 10, dd = n & (DM - 1);
                const float* bb = (proj == 0) ? b0 : (proj == 1) ? b1 : b2;
                ushort* Cb      = (ushort*)((proj == 0) ? C0v : (proj == 1) ? C1v : C2v);
                float bv = bb[dd];
                int b = m0 >> 11, l = m0 & (LSEQ - 1);
                ushort4 val;
                val.x = f2b(acc[i][j][0] + bv);
                val.y = f2b(acc[i][j][1] + bv);
                val.z = f2b(acc[i][j][2] + bv);
                val.w = f2b(acc[i][j][3] + bv);
                *(ushort4*)(Cb + ((size_t)b * DM + dd) * LSEQ + l) = val;
            } else {
                float* C0 = (float*)C0v;
                float bv = b0[n];
#pragma unroll
                for (int r = 0; r < 4; ++r)
                    C0[(size_t)(m0 + r) * N + n] = acc[i][j][r] + bv;
            }
        }
    }
}

// ---------------------------------------------------------------- MFMA Toeplitz causal conv (bf16 in/out)
#define KSTR 2096            // krev: krev[i] = Kpad[2095-i]; Kpad = 32 zeros | ker | 16 zeros
#define XSTR 2248            // elems: 128 front zeros + 2048 + 32 tail zeros + pad

__global__ __launch_bounds__(512) void conv_mfma_kernel(const ushort* __restrict__ x,
                                                        const float* __restrict__ ker,
                                                        const float* __restrict__ scale,
                                                        const ushort* __restrict__ gate,
                                                        ushort* __restrict__ out) {
    __shared__ ushort krev[KSTR];
    __shared__ ushort xs[4 * XSTR];
    const int d    = blockIdx.x;
    const int tid  = threadIdx.x;
    const int wave = tid >> 6;
    const int lane = tid & 63;

    // ---- stage x rows (4 batches) via global_load_lds: wave w -> batch w>>1, half w&1
    {
        int b = wave >> 1, half = wave & 1;
        const ushort* src = x + ((size_t)b * DM + d) * LSEQ + half * 1024 + lane * 8;
        char* dst = (char*)xs + b * (XSTR * 2) + 256 + half * 2048;
#pragma unroll
        for (int c = 0; c < 2; ++c)
            __builtin_amdgcn_global_load_lds((const __attribute__((address_space(1))) void*)(src + c * 512),
                                             (__attribute__((address_space(3))) void*)(dst + c * 1024),
                                             16, 0, 0);
    }
    // ---- stage reversed kernel as bf16: thread t covers ker[4t..4t+3]
    {
        const float* krow = ker + (size_t)d * LSEQ;
        int e0 = tid * 4;
        float4 kv = *(const float4*)(krow + e0);
        ushort4 o;                                    // krev[2060-e0 + j] = ker[e0+3-j]
        o.x = f2b(kv.w); o.y = f2b(kv.z); o.z = f2b(kv.y); o.w = f2b(kv.x);
        *(ushort4*)(krev + (2060 - e0)) = o;
        uint4 z = {0, 0, 0, 0};
        if (tid < 2)  *(uint4*)((char*)krev + tid * 16) = z;
        if (tid >= 2 && tid < 6) *(uint4*)((char*)krev + 4128 + (tid - 2) * 16) = z;
        if (tid >= 64 && tid < 128) {
            int b = (tid - 64) >> 4, c = (tid - 64) & 15;
            *(uint4*)((char*)xs + b * (XSTR * 2) + c * 16) = z;
        }
        if (tid >= 128 && tid < 144) {
            int b = (tid - 128) >> 2, c = (tid - 128) & 3;
            *(uint4*)((char*)xs + b * (XSTR * 2) + 4352 + c * 16) = z;
        }
    }
    __syncthreads();

    const int qn = lane & 15;
    const int qk = lane >> 4;

    int g[2] = {wave, 15 - wave};
    const int smax_all = 128 * (15 - wave) + 128;

    const int lbase = (qn & 3) * XSTR + 128 + 16 * (qn >> 2) + 8 * qk;

    floatx4 acc[2][2] = {};

    short8 fE[2], fO[2];
#pragma unroll
    for (int gi = 0; gi < 2; ++gi) {
        fE[gi] = *(const short8*)(xs + lbase + 128 * g[gi] + 64);
        fO[gi] = *(const short8*)(xs + lbase + 128 * g[gi] + 32);
    }

#define CSTEP(SS, FP)                                                                        \
    {                                                                                        \
        int b_el = 2063 - qn + 8 * qk - (SS);                                                \
        int A0 = b_el & ~3;                                                                  \
        uint2 w0 = *(const uint2*)(krev + A0);                                               \
        uint2 w1 = *(const uint2*)(krev + A0 + 4);                                           \
        uint2 w2 = *(const uint2*)(krev + A0 + 8);                                           \
        int qsel = (b_el >> 1) & 1;                                                          \
        uint sh  = (uint)(b_el & 1) * 16u;                                                   \
        uint e0 = qsel ? w0.y : w0.x;                                                        \
        uint e1 = qsel ? w1.x : w0.y;                                                        \
        uint e2 = qsel ? w1.y : w1.x;                                                        \
        uint e3 = qsel ? w2.x : w1.y;                                                        \
        uint e4 = qsel ? w2.y : w2.x;                                                        \
        union { uint u[4]; short8 v; } Af;                                                   \
        Af.u[0] = __builtin_amdgcn_alignbit(e1, e0, sh);                                     \
        Af.u[1] = __builtin_amdgcn_alignbit(e2, e1, sh);                                     \
        Af.u[2] = __builtin_amdgcn_alignbit(e3, e2, sh);                                     \
        Af.u[3] = __builtin_amdgcn_alignbit(e4, e3, sh);                                     \
        _Pragma("unroll")                                                                    \
        for (int gi = 0; gi < 2; ++gi) {                                                     \
            if ((SS) <= 128 * g[gi] + 128) {                                                 \
                short8 fN = *(const short8*)(xs + lbase + 128 * g[gi] - (SS));               \
                acc[gi][0] = __builtin_amdgcn_mfma_f32_16x16x32_bf16(Af.v, fN, acc[gi][0], 0, 0, 0); \
                acc[gi][1] = __builtin_amdgcn_mfma_f32_16x16x32_bf16(Af.v, FP[gi], acc[gi][1], 0, 0, 0); \
                FP[gi] = fN;                                                                 \
            }                                                                                \
        }                                                                                    \
    }

    for (int s = 0; s <= smax_all; s += 64) {
        CSTEP(s, fE);
        if (s + 32 <= smax_all) CSTEP(s + 32, fO);
    }
#undef CSTEP

    const float sc = scale[d];
#pragma unroll
    for (int gi = 0; gi < 2; ++gi) {
#pragma unroll
        for (int m = 0; m < 2; ++m) {
            int p  = 8 * g[gi] + 4 * m + (qn >> 2);
            int b  = qn & 3;
            int l0 = 16 * p + 4 * qk;
            size_t off = ((size_t)b * DM + d) * LSEQ + l0;
            ushort4 xv = *(const ushort4*)(xs + b * XSTR + 128 + l0);
            ushort4 gv = *(const ushort4*)(gate + off);
            ushort4 ov;
            ov.x = f2b((acc[gi][m][0] + sc * b2f(xv.x)) * b2f(gv.x));
            ov.y = f2b((acc[gi][m][1] + sc * b2f(xv.y)) * b2f(gv.y));
            ov.z = f2b((acc[gi][m][2] + sc * b2f(xv.z)) * b2f(gv.z));
            ov.w = f2b((acc[gi][m][3] + sc * b2f(xv.w)) * b2f(gv.w));
            *(ushort4*)(out + off) = ov;
        }
    }
}

// ---------------------------------------------------------------- (B,DM,L) bf16 -> (B*L,DM) bf16
__global__ __launch_bounds__(256) void transpose_bf16(const ushort* __restrict__ in,
                                                      ushort* __restrict__ out) {
    __shared__ ushort t[32][36];
    const int l0 = blockIdx.x * 32;
    const int d0 = blockIdx.y * 32;
    const int b  = blockIdx.z;
    const int q  = threadIdx.x & 7;
    const int r  = threadIdx.x >> 3;
    *(ushort4*)(&t[r][q * 4]) = *(const ushort4*)(in + ((size_t)b * DM + d0 + r) * LSEQ + l0 + q * 4);
    __syncthreads();
    ushort4 o;
    o.x = t[q * 4 + 0][r]; o.y = t[q * 4 + 1][r]; o.z = t[q * 4 + 2][r]; o.w = t[q * 4 + 3][r];
    *(ushort4*)(out + ((size_t)b * LSEQ + l0 + r) * DM + d0 + q * 4) = o;
}

// ---------------------------------------------------------------- launch
extern "C" void kernel_launch(void* const* d_in, const int* in_sizes, int n_in,
                              void* d_out, int out_size, void* d_ws, size_t ws_size,
                              hipStream_t stream) {
    const float* u        = (const float*)d_in[0];
    const float* Wq       = (const float*)d_in[1];
    const float* bq       = (const float*)d_in[2];
    const float* Wk       = (const float*)d_in[3];
    const float* bk       = (const float*)d_in[4];
    const float* Wv       = (const float*)d_in[5];
    const float* bv       = (const float*)d_in[6];
    const float* k_kernel = (const float*)d_in[7];
    const float* k_D      = (const float*)d_in[8];
    const float* ssm_ker  = (const float*)d_in[9];
    const float* Dv       = (const float*)d_in[10];
    const float* Wo       = (const float*)d_in[11];
    const float* bo       = (const float*)d_in[12];
    float* outp = (float*)d_out;

    char* ws = (char*)d_ws;
    ushort* Q    = (ushort*)(ws);                    // 16 MB (bf16 b,d,l)
    ushort* KV   = (ushort*)(ws + (16ull << 20));    // 16 MB (k -> kv -> yq, in place)
    ushort* V    = (ushort*)(ws + (32ull << 20));    // 16 MB
    ushort* U16  = (ushort*)(ws + (48ull << 20));    // 16 MB (u bf16)
    ushort* YT   = (ushort*)(ws + (64ull << 20));    // 16 MB (yq transposed)
    ushort* Wcat = (ushort*)(ws + (80ull << 20));    // 8 MB  (Wq|Wk|Wv|Wo bf16)

    cvt_bf16_kernel<<<(NB * LSEQ * DM / 8) / 256, 256, 0, stream>>>(u, U16, NB * LSEQ * DM / 8);
    cvt_w_kernel<<<(4 * DM * DM / 8) / 256, 256, 0, stream>>>(Wq, Wk, Wv, Wo, Wcat);

    // fused q/k/v projection: M=(b,l)=8192, N=3*DM, K=DM; bf16 outputs
    dim3 g1(3 * DM / 256, NB * LSEQ / 128);
    gemm_bt2<0><<<g1, 512, 0, stream>>>(U16, Wcat, bq, bk, bv, Q, KV, V,
                                        NB * LSEQ, 3 * DM, DM, 3 * DM / 256);

    // kv = (k_kernel (*) k + k_D*k) * v
    conv_mfma_kernel<<<DM, 512, 0, stream>>>(KV, k_kernel, k_D, V, KV);
    // yq = (ssm_kernel (*) kv + D*kv) * q
    conv_mfma_kernel<<<DM, 512, 0, stream>>>(KV, ssm_ker, Dv, Q, KV);

    // (B,DM,L) bf16 -> (B*L,DM) bf16
    dim3 g2(LSEQ / 32, DM / 32, NB);
    transpose_bf16<<<g2, 256, 0, stream>>>(KV, YT);

    // out = YT @ Wo^T + bo : M=(b,l), N=o, K=h ; f32 output
    dim3 g3(DM / 256, NB * LSEQ / 128);
    gemm_bt2<1><<<g3, 512, 0, stream>>>(YT, Wcat + 3 * DM * DM, bo, bo, bo,
                                        outp, outp, outp, NB * LSEQ, DM, DM, DM / 256);
}